// Round 4
// baseline (162.095 us; speedup 1.0000x reference)
//
#include <hip/hip_runtime.h>
#include <cstdint>

#define BATCH 64
#define NPIX 65536
#define TOPK 16384
#define NB 256        // value bins: key = floor(v*256), v in [0,1)
#define SEGS 32       // k1 blocks per batch
#define CAP 2048      // LDS candidate capacity (expected ~256/batch)

__device__ __forceinline__ float block_reduce(float acc) {
    __shared__ float w[4];
    #pragma unroll
    for (int off = 32; off > 0; off >>= 1) acc += __shfl_down(acc, off, 64);
    if ((threadIdx.x & 63) == 0) w[threadIdx.x >> 6] = acc;
    __syncthreads();
    return w[0] + w[1] + w[2] + w[3];
}

// p = softmax(a0,a1)[0] = sigmoid(d), d = a0-a1.
// lp = log p = min(d,0) - t ; llp = log(1-p) = -max(d,0) - t,
// t = log(1+exp(-|d|)). Clamped at -100 per torch BCELoss.
__device__ __forceinline__ void bce_from_d(float d, float& lp, float& llp) {
    float t = __logf(1.f + __expf(-fabsf(d)));
    lp  = fmaxf(fminf(d, 0.f) - t, -100.f);
    llp = fmaxf(-fmaxf(d, 0.f) - t, -100.f);
}

__device__ __forceinline__ int vkey(float v) {
    return (int)fminf(v * 256.0f, 255.0f);   // monotone bucket map, v in [0,1)
}

// ---------------------------------------------------------------------------
// K1: one pass over all 80MB. SEGS blocks per batch, 2048 px each.
// Outputs: per-block 256-bin {count, sum(lp-llp)} sub-histogram (plain
// stores, fully written -> no pre-zero), per-block sum(llp) partial.
// ---------------------------------------------------------------------------
__global__ __launch_bounds__(256) void k1_hist_base(
    const float4* __restrict__ sc, const float4* __restrict__ gn,
    const float2* __restrict__ tokp,
    uint32_t* __restrict__ gc, float* __restrict__ gs,
    float* __restrict__ pk1)
{
    __shared__ uint32_t hc[NB];
    __shared__ float hs[NB];
    const int tid = threadIdx.x;
    hc[tid] = 0u; hs[tid] = 0.f;
    __syncthreads();

    const int b   = blockIdx.x >> 5;
    const int seg = blockIdx.x & (SEGS - 1);
    const int pairbase = b * (NPIX / 2) + seg * 1024;   // 1024 pairs / block
    float acc = 0.f;

    #pragma unroll
    for (int it = 0; it < 4; ++it) {
        int j = pairbase + it * 256 + tid;
        float4 s = sc[j];
        float4 g = gn[j];
        float2 tk = tokp[j];
        {
            float d = (s.x + g.x) - (s.y + g.y);
            float lp, llp; bce_from_d(d, lp, llp);
            acc += llp;
            int k = vkey(tk.x);
            atomicAdd(&hc[k], 1u);
            atomicAdd(&hs[k], lp - llp);
        }
        {
            float d = (s.z + g.z) - (s.w + g.w);
            float lp, llp; bce_from_d(d, lp, llp);
            acc += llp;
            int k = vkey(tk.y);
            atomicAdd(&hc[k], 1u);
            atomicAdd(&hs[k], lp - llp);
        }
    }
    __syncthreads();
    const size_t o = (size_t)blockIdx.x * NB + tid;   // [b][seg][bin]
    gc[o] = hc[tid];
    gs[o] = hs[tid];
    float tot = block_reduce(acc);
    if (tid == 0) pk1[blockIdx.x] = tot;
}

// ---------------------------------------------------------------------------
// K34: one block per batch. Merge sub-hists -> parallel suffix scan ->
// threshold bin sb, remainder rem, sum(diff) over bins above sb. Then scan
// this batch's s_map (L3-hot), compact key==sb hits into LDS, rank exactly
// under (value desc, index asc) == lax.top_k tie order, add selected diffs.
// ---------------------------------------------------------------------------
__global__ __launch_bounds__(256) void k34_select(
    const float4* __restrict__ tok4,
    const uint32_t* __restrict__ gc, const float* __restrict__ gs,
    const float2* __restrict__ sc2, const float2* __restrict__ gn2,
    float* __restrict__ pk34)
{
    __shared__ uint32_t sufc[2][NB];
    __shared__ float    sufs[2][NB];
    __shared__ uint32_t cvb[CAP];
    __shared__ uint32_t cvi[CAP];
    __shared__ uint32_t lcnt;
    __shared__ int sh_sb;
    __shared__ uint32_t sh_rem;
    __shared__ float sh_sa;

    const int b = blockIdx.x, tid = threadIdx.x;

    // merge SEGS sub-histograms (coalesced: consecutive tid -> consecutive bin)
    uint32_t c = 0; float s = 0.f;
    for (int sg = 0; sg < SEGS; ++sg) {
        size_t o = (size_t)(b * SEGS + sg) * NB + tid;
        c += gc[o];
        s += gs[o];
    }
    sufc[0][tid] = c; sufs[0][tid] = s;
    if (tid == 0) lcnt = 0;
    __syncthreads();

    // inclusive suffix sums over bins (Hillis-Steele, 8 steps)
    int cur = 0;
    #pragma unroll
    for (int off = 1; off < NB; off <<= 1) {
        uint32_t cc = sufc[cur][tid];
        float ss = sufs[cur][tid];
        if (tid + off < NB) { cc += sufc[cur][tid + off]; ss += sufs[cur][tid + off]; }
        sufc[cur ^ 1][tid] = cc; sufs[cur ^ 1][tid] = ss;
        cur ^= 1;
        __syncthreads();
    }
    // S[bin] = #elements with key >= bin. Find sb: S[sb] >= K > S[sb+1].
    {
        uint32_t Sme = sufc[cur][tid];
        uint32_t Snx = (tid < NB - 1) ? sufc[cur][tid + 1] : 0u;
        if (Sme >= TOPK && Snx < TOPK) {
            sh_sb  = tid;
            sh_rem = TOPK - Snx;
            sh_sa  = (tid < NB - 1) ? sufs[cur][tid + 1] : 0.f;
        }
    }
    __syncthreads();
    const int sb = sh_sb;

    // compact candidates with key == sb from this batch's s_map
    const float4* base = tok4 + (size_t)b * (NPIX / 4);
    #pragma unroll 4
    for (int it = 0; it < 64; ++it) {
        int j = it * 256 + tid;
        float4 v = base[j];
        int px = j * 4;
        float fv[4] = {v.x, v.y, v.z, v.w};
        #pragma unroll
        for (int q = 0; q < 4; ++q) {
            if (vkey(fv[q]) == sb) {
                uint32_t p = atomicAdd(&lcnt, 1u);
                if (p < CAP) { cvb[p] = __float_as_uint(fv[q]); cvi[p] = (uint32_t)(px + q); }
            }
        }
    }
    __syncthreads();
    const uint32_t cnt = min(lcnt, (uint32_t)CAP);
    const uint32_t rem = sh_rem;

    float acc = (tid == 0) ? sh_sa : 0.f;
    for (uint32_t j = tid; j < cnt; j += 256) {
        const uint32_t mb = cvb[j], mi = cvi[j];
        uint32_t rank = 0;
        for (uint32_t i = 0; i < cnt; ++i) {
            uint32_t ob = cvb[i];
            rank += (ob > mb) || (ob == mb && cvi[i] < mi);
        }
        if (rank < rem) {
            size_t idx = (size_t)b * NPIX + mi;
            float2 S = sc2[idx];
            float2 G = gn2[idx];
            float d = (S.x + G.x) - (S.y + G.y);
            float lp, llp; bce_from_d(d, lp, llp);
            acc += lp - llp;
        }
    }
    float tot = block_reduce(acc);
    if (tid == 0) pk34[b] = tot;
}

// ---------------------------------------------------------------------------
// K5: sum all partials, out = -(total).
// ---------------------------------------------------------------------------
#define NPART (BATCH * SEGS + BATCH)
__global__ __launch_bounds__(256) void k5_reduce(
    const float* __restrict__ parts, float* __restrict__ out)
{
    float acc = 0.f;
    for (int i = threadIdx.x; i < NPART; i += 256) acc += parts[i];
    float tot = block_reduce(acc);
    if (threadIdx.x == 0) out[0] = -tot;
}

extern "C" void kernel_launch(void* const* d_in, const int* in_sizes, int n_in,
                              void* d_out, int out_size, void* d_ws, size_t ws_size,
                              hipStream_t stream) {
    const float* scores = (const float*)d_in[0];   // [B, N, 2]
    const float* smap   = (const float*)d_in[1];   // [B, N]
    const float* gumbel = (const float*)d_in[2];   // [B, N, 2]
    float* out = (float*)d_out;

    // workspace (all regions fully written before read -> no zero-init)
    char* ws = (char*)d_ws;
    uint32_t* gc   = (uint32_t*)ws;  ws += (size_t)BATCH * SEGS * NB * 4;  // 2MB
    float*    gs   = (float*)ws;     ws += (size_t)BATCH * SEGS * NB * 4;  // 2MB
    float*    pall = (float*)ws;     // [BATCH*SEGS + BATCH]
    float*    pk1  = pall;
    float*    pk34 = pall + BATCH * SEGS;

    k1_hist_base<<<BATCH * SEGS, 256, 0, stream>>>(
        (const float4*)scores, (const float4*)gumbel, (const float2*)smap,
        gc, gs, pk1);

    k34_select<<<BATCH, 256, 0, stream>>>(
        (const float4*)smap, gc, gs,
        (const float2*)scores, (const float2*)gumbel, pk34);

    k5_reduce<<<1, 256, 0, stream>>>(pall, out);
}

// Round 6
// 148.923 us; speedup vs baseline: 1.0884x; 1.0884x over previous
//
#include <hip/hip_runtime.h>
#include <cstdint>

#define BATCH 64
#define NPIX 65536
#define TOPK 16384
#define NB 256          // value bins: key = floor(v*256), v in [0,1)
#define SEGS 32         // k1 blocks per batch
#define MAXCAND 2048    // global candidates per batch (expected ~256)
#define CCNT_STRIDE 32  // u32 stride -> 128B per counter, no line sharing
#define LBUF 512        // per-block LDS candidate capacity (expected ~16)

__device__ __forceinline__ float block_reduce(float acc) {
    __shared__ float w[4];
    #pragma unroll
    for (int off = 32; off > 0; off >>= 1) acc += __shfl_down(acc, off, 64);
    if ((threadIdx.x & 63) == 0) w[threadIdx.x >> 6] = acc;
    __syncthreads();
    return w[0] + w[1] + w[2] + w[3];
}

// p = softmax(a0,a1)[0] = sigmoid(d), d = a0-a1.
// lp = log p = min(d,0) - t ; llp = log(1-p) = -max(d,0) - t,
// t = log(1+exp(-|d|)). Clamped at -100 per torch BCELoss.
__device__ __forceinline__ void bce_from_d(float d, float& lp, float& llp) {
    float t = __logf(1.f + __expf(-fabsf(d)));
    lp  = fmaxf(fminf(d, 0.f) - t, -100.f);
    llp = fmaxf(-fmaxf(d, 0.f) - t, -100.f);
}

__device__ __forceinline__ int vkey(float v) {
    return (int)fminf(v * 256.0f, 255.0f);   // monotone bucket map, v in [0,1)
}

// ---------------------------------------------------------------------------
// K1: one pass over all 80MB. SEGS blocks/batch, 2048 px each. Outputs
// per-block 256-bin {count, sum(lp-llp)} sub-hist (plain stores, fully
// written -> no pre-zero) and per-block sum(llp) partial.
// ---------------------------------------------------------------------------
__global__ __launch_bounds__(256) void k1_hist_base(
    const float4* __restrict__ sc, const float4* __restrict__ gn,
    const float2* __restrict__ tokp,
    uint32_t* __restrict__ gc, float* __restrict__ gs,
    float* __restrict__ pk1)
{
    __shared__ uint32_t hc[NB];
    __shared__ float hs[NB];
    const int tid = threadIdx.x;
    hc[tid] = 0u; hs[tid] = 0.f;
    __syncthreads();

    const int b   = blockIdx.x >> 5;
    const int seg = blockIdx.x & (SEGS - 1);
    const int pairbase = b * (NPIX / 2) + seg * 1024;   // 1024 pairs / block
    float acc = 0.f;

    #pragma unroll
    for (int it = 0; it < 4; ++it) {
        int j = pairbase + it * 256 + tid;
        float4 s = sc[j];
        float4 g = gn[j];
        float2 tk = tokp[j];
        {
            float d = (s.x + g.x) - (s.y + g.y);
            float lp, llp; bce_from_d(d, lp, llp);
            acc += llp;
            int k = vkey(tk.x);
            atomicAdd(&hc[k], 1u);
            atomicAdd(&hs[k], lp - llp);
        }
        {
            float d = (s.z + g.z) - (s.w + g.w);
            float lp, llp; bce_from_d(d, lp, llp);
            acc += llp;
            int k = vkey(tk.y);
            atomicAdd(&hc[k], 1u);
            atomicAdd(&hs[k], lp - llp);
        }
    }
    __syncthreads();
    const size_t o = (size_t)blockIdx.x * NB + tid;   // [b][seg][bin]
    gc[o] = hc[tid];
    gs[o] = hs[tid];
    float tot = block_reduce(acc);
    if (tid == 0) pk1[blockIdx.x] = tot;
}

// ---------------------------------------------------------------------------
// K2: per batch, merge sub-hists + parallel suffix scan -> threshold bin,
// remainder, sum(diff) above. All outputs unconditionally written by tid 0
// (staged through LDS with safe defaults). Also zeroes candidate counter.
// ---------------------------------------------------------------------------
__global__ __launch_bounds__(256) void k2_scan(
    const uint32_t* __restrict__ gc, const float* __restrict__ gs,
    int* __restrict__ selb, uint32_t* __restrict__ remv,
    uint32_t* __restrict__ ccnt, float* __restrict__ pk2)
{
    __shared__ uint32_t sufc[2][NB];
    __shared__ float    sufs[2][NB];
    __shared__ int      sh_sb;
    __shared__ uint32_t sh_rem;
    __shared__ float    sh_sa;
    const int b = blockIdx.x, tid = threadIdx.x;

    if (tid == 0) { sh_sb = 0; sh_rem = 0u; sh_sa = 0.f; }

    uint32_t c = 0; float s = 0.f;
    for (int sg = 0; sg < SEGS; ++sg) {
        size_t o = (size_t)(b * SEGS + sg) * NB + tid;
        c += gc[o];
        s += gs[o];
    }
    sufc[0][tid] = c; sufs[0][tid] = s;
    __syncthreads();

    int cur = 0;
    #pragma unroll
    for (int off = 1; off < NB; off <<= 1) {
        uint32_t cc = sufc[cur][tid];
        float ss = sufs[cur][tid];
        if (tid + off < NB) { cc += sufc[cur][tid + off]; ss += sufs[cur][tid + off]; }
        sufc[cur ^ 1][tid] = cc; sufs[cur ^ 1][tid] = ss;
        cur ^= 1;
        __syncthreads();
    }
    // S[bin] = #elements with key >= bin; unique sb with S[sb] >= K > S[sb+1]
    uint32_t Sme = sufc[cur][tid];
    uint32_t Snx = (tid < NB - 1) ? sufc[cur][tid + 1] : 0u;
    if (Sme >= TOPK && Snx < TOPK) {
        sh_sb  = tid;
        sh_rem = TOPK - Snx;
        sh_sa  = (tid < NB - 1) ? sufs[cur][tid + 1] : 0.f;
    }
    __syncthreads();
    if (tid == 0) {
        selb[b] = sh_sb;                 // always in [0, 255]
        remv[b] = sh_rem;
        pk2[b]  = sh_sa;
        ccnt[b * CCNT_STRIDE] = 0u;
    }
}

// ---------------------------------------------------------------------------
// K3: 16 blocks/batch re-scan of s_map (L3-hot). LDS compaction of
// threshold-bin hits; ONE padded global atomic per block; coalesced copy-out.
// ---------------------------------------------------------------------------
__global__ __launch_bounds__(256) void k3_gather(
    const float4* __restrict__ tok4, const int* __restrict__ selb,
    uint32_t* __restrict__ ccnt, uint2* __restrict__ cand)
{
    __shared__ uint2 lbuf[LBUF];
    __shared__ uint32_t lcnt, lbase;
    const int tid = threadIdx.x;
    if (tid == 0) lcnt = 0;
    __syncthreads();

    const int b   = blockIdx.x >> 4;
    const int seg = blockIdx.x & 15;
    const int base4 = b * (NPIX / 4) + seg * 1024;   // 4096 px per block
    const int sb = selb[b] & 0xFF;                   // defensively in-range

    #pragma unroll
    for (int it = 0; it < 4; ++it) {
        int j = base4 + it * 256 + tid;
        float4 v = tok4[j];
        int px = j * 4;
        float fv[4] = {v.x, v.y, v.z, v.w};
        #pragma unroll
        for (int q = 0; q < 4; ++q) {
            if (vkey(fv[q]) == sb) {
                uint32_t p = atomicAdd(&lcnt, 1u);
                if (p < LBUF)
                    lbuf[p] = make_uint2(__float_as_uint(fv[q]), (uint32_t)(px + q));
            }
        }
    }
    __syncthreads();
    uint32_t n = min(lcnt, (uint32_t)LBUF);
    if (tid == 0) lbase = atomicAdd(&ccnt[b * CCNT_STRIDE], n);
    __syncthreads();
    uint32_t bs = lbase;
    for (uint32_t j = tid; j < n; j += 256) {
        uint32_t pos = bs + j;
        if (pos < MAXCAND) cand[b * MAXCAND + pos] = lbuf[j];
    }
}

// ---------------------------------------------------------------------------
// K4: per batch, exact rank under (value desc, index asc) == lax.top_k tie
// order; selected candidates contribute diff = lp - llp. Plain store.
// All gather indices masked into range -> OOB structurally impossible.
// ---------------------------------------------------------------------------
__global__ __launch_bounds__(256) void k4_finalize(
    const uint2* __restrict__ cand, const uint32_t* __restrict__ ccnt,
    const uint32_t* __restrict__ remv,
    const float2* __restrict__ sc2, const float2* __restrict__ gn2,
    float* __restrict__ pk4)
{
    __shared__ uint32_t vb[MAXCAND];
    __shared__ uint32_t vi[MAXCAND];
    const int b = blockIdx.x, tid = threadIdx.x;
    const uint32_t cnt = min(ccnt[b * CCNT_STRIDE], (uint32_t)MAXCAND);
    const uint32_t rem = min(remv[b], (uint32_t)NPIX);
    for (uint32_t j = tid; j < cnt; j += 256) {
        uint2 e = cand[b * MAXCAND + j];
        vb[j] = e.x;
        vi[j] = e.y & (NPIX - 1);        // mask: no poisoned index can escape
    }
    __syncthreads();
    float acc = 0.f;
    for (uint32_t j = tid; j < cnt; j += 256) {
        const uint32_t mb = vb[j], mi = vi[j];
        uint32_t rank = 0;
        for (uint32_t i = 0; i < cnt; ++i) {
            uint32_t ob = vb[i];
            rank += (ob > mb) || (ob == mb && vi[i] < mi);
        }
        if (rank < rem) {
            size_t idx = (size_t)b * NPIX + mi;    // mi < NPIX guaranteed
            float2 S = sc2[idx];
            float2 G = gn2[idx];
            float d = (S.x + G.x) - (S.y + G.y);
            float lp, llp; bce_from_d(d, lp, llp);
            acc += lp - llp;
        }
    }
    float tot = block_reduce(acc);
    if (tid == 0) pk4[b] = tot;
}

// ---------------------------------------------------------------------------
// K5: sum all partials, out = -(total).
// ---------------------------------------------------------------------------
#define NPART (BATCH * SEGS + BATCH + BATCH)
__global__ __launch_bounds__(256) void k5_reduce(
    const float* __restrict__ parts, float* __restrict__ out)
{
    float acc = 0.f;
    for (int i = threadIdx.x; i < NPART; i += 256) acc += parts[i];
    float tot = block_reduce(acc);
    if (threadIdx.x == 0) out[0] = -tot;
}

extern "C" void kernel_launch(void* const* d_in, const int* in_sizes, int n_in,
                              void* d_out, int out_size, void* d_ws, size_t ws_size,
                              hipStream_t stream) {
    const float* scores = (const float*)d_in[0];   // [B, N, 2]
    const float* smap   = (const float*)d_in[1];   // [B, N]
    const float* gumbel = (const float*)d_in[2];   // [B, N, 2]
    float* out = (float*)d_out;

    // workspace: every region fully written before read -> NO memset needed
    char* ws = (char*)d_ws;
    uint32_t* gc   = (uint32_t*)ws;  ws += (size_t)BATCH * SEGS * NB * 4;   // 2MB
    float*    gs   = (float*)ws;     ws += (size_t)BATCH * SEGS * NB * 4;   // 2MB
    uint32_t* ccnt = (uint32_t*)ws;  ws += (size_t)BATCH * CCNT_STRIDE * 4; // 8KB (zeroed by k2)
    int*      selb = (int*)ws;       ws += BATCH * 4;
    uint32_t* remv = (uint32_t*)ws;  ws += BATCH * 4;
    float*    pall = (float*)ws;     ws += NPART * 4;
    float*    pk1  = pall;
    float*    pk2  = pall + BATCH * SEGS;
    float*    pk4  = pall + BATCH * SEGS + BATCH;
    uint2*    cand = (uint2*)ws;

    k1_hist_base<<<BATCH * SEGS, 256, 0, stream>>>(
        (const float4*)scores, (const float4*)gumbel, (const float2*)smap,
        gc, gs, pk1);

    k2_scan<<<BATCH, 256, 0, stream>>>(gc, gs, selb, remv, ccnt, pk2);

    k3_gather<<<BATCH * 16, 256, 0, stream>>>((const float4*)smap, selb, ccnt, cand);

    k4_finalize<<<BATCH, 256, 0, stream>>>(
        cand, ccnt, remv, (const float2*)scores, (const float2*)gumbel, pk4);

    k5_reduce<<<1, 256, 0, stream>>>(pall, out);
}